// Round 8
// baseline (235.477 us; speedup 1.0000x reference)
//
#include <hip/hip_runtime.h>

#define N_NODES 100000
#define N_EDGES 1200000
#define CH 64
#define NG 256
#define OC 8
#define NBUK 196        // ceil(N_NODES/512)
#define BINCHUNK 4096
#define NBLKA 293       // ceil(N_EDGES/BINCHUNK)
#define NSTRIP 6250     // N_NODES/16 (exact)

typedef unsigned short ushort_t;
typedef unsigned int uint_t;
typedef __attribute__((ext_vector_type(8))) short bf16x8;
typedef __attribute__((ext_vector_type(4))) float f32x4;

__device__ __forceinline__ ushort_t f2bf(float f) {  // RNE f32->bf16
  uint_t u = __float_as_uint(f);
  return (ushort_t)((u + 0x7FFFu + ((u >> 16) & 1u)) >> 16);
}
__device__ __forceinline__ float bfE(uint_t u) {  // even channel (low 16)
  return __uint_as_float(u << 16);
}
__device__ __forceinline__ float bfO(uint_t u) {  // odd channel (high 16)
  return __uint_as_float(u & 0xFFFF0000u);
}

// ---------------- pass A1: per-bucket totals (dst>>9) ----------------
__global__ __launch_bounds__(256) void countA_k(const int* __restrict__ dst,
                                                int* __restrict__ gbase) {
  __shared__ int hist[NBUK];
  for (int i = threadIdx.x; i < NBUK; i += 256) hist[i] = 0;
  __syncthreads();
  const int cs = blockIdx.x * BINCHUNK;
  int ce = cs + BINCHUNK;
  if (ce > N_EDGES) ce = N_EDGES;
  for (int e = cs + threadIdx.x; e < ce; e += 256)
    atomicAdd(&hist[dst[e] >> 9], 1);
  __syncthreads();
  for (int b = threadIdx.x; b < NBUK; b += 256) {
    int c = hist[b];
    if (c) atomicAdd(&gbase[b], c);
  }
}

// ---------------- pass B: exclusive scan -> boff; cursor = boff ----------------
__global__ void scanB_k(const int* __restrict__ gbase, int* __restrict__ boff,
                        int* __restrict__ cursor) {
  __shared__ int s[256];
  int v = (threadIdx.x < NBUK) ? gbase[threadIdx.x] : 0;
  s[threadIdx.x] = v;
  __syncthreads();
  for (int o = 1; o < 256; o <<= 1) {
    int t = (threadIdx.x >= o) ? s[threadIdx.x - o] : 0;
    __syncthreads();
    s[threadIdx.x] += t;
    __syncthreads();
  }
  if (threadIdx.x < NBUK) {
    int ex = s[threadIdx.x] - v;
    boff[threadIdx.x] = ex;
    cursor[threadIdx.x] = ex;
  }
  if (threadIdx.x == NBUK - 1) boff[NBUK] = s[threadIdx.x];
}

// ---------------- pass A2: scatter packed edges into bucket regions ----------------
__global__ __launch_bounds__(256) void scatterA_k(const int* __restrict__ src,
                                                  const int* __restrict__ dst,
                                                  int* __restrict__ cursor,
                                                  int* __restrict__ tmp) {
  __shared__ int hist[NBUK];
  for (int i = threadIdx.x; i < NBUK; i += 256) hist[i] = 0;
  __syncthreads();
  const int cs = blockIdx.x * BINCHUNK;
  int ce = cs + BINCHUNK;
  if (ce > N_EDGES) ce = N_EDGES;
  for (int e = cs + threadIdx.x; e < ce; e += 256)
    atomicAdd(&hist[dst[e] >> 9], 1);
  __syncthreads();
  for (int b = threadIdx.x; b < NBUK; b += 256) {
    int c = hist[b];
    hist[b] = c ? atomicAdd(&cursor[b], c) : 0;
  }
  __syncthreads();
  for (int e = cs + threadIdx.x; e < ce; e += 256) {
    int d = dst[e];
    int slot = atomicAdd(&hist[d >> 9], 1);
    tmp[slot] = (src[e] << 9) | (d & 511);
  }
}

// ---------------- pass C: per-bucket fine CSR (rowptr + col) ----------------
__global__ __launch_bounds__(512) void csrC_k(const int* __restrict__ tmp,
                                              const int* __restrict__ boff,
                                              int* __restrict__ rp,
                                              int* __restrict__ col) {
  __shared__ int lh[512];
  __shared__ int s[512];
  const int b = blockIdx.x;
  const int tid = threadIdx.x;
  const int eb = boff[b], ee = boff[b + 1];
  lh[tid] = 0;
  __syncthreads();
  for (int e = eb + tid; e < ee; e += 512) atomicAdd(&lh[tmp[e] & 511], 1);
  __syncthreads();
  int v = lh[tid];
  s[tid] = v;
  __syncthreads();
  for (int o = 1; o < 512; o <<= 1) {
    int t = (tid >= o) ? s[tid - o] : 0;
    __syncthreads();
    s[tid] += t;
    __syncthreads();
  }
  const int base = eb + s[tid] - v;
  const int node = b * 512 + tid;
  if (node < N_NODES) rp[node] = base;
  if (b == 0 && tid == 0) rp[N_NODES] = N_EDGES;
  lh[tid] = base;
  __syncthreads();
  for (int e = eb + tid; e < ee; e += 512) {
    int p = tmp[e];
    int slot = atomicAdd(&lh[p & 511], 1);
    col[slot] = p >> 9;
  }
}

// ---------------- MFMA dual transform: outl/outr (bf16) = in@Wl^T / in@Wr^T ----
// One wave per 16-node strip. TIN = float (layer 1) or ushort_t/bf16 (layer 2).
// A-row / B-col bound to lane&15; same k-grouping for A and B (perm-safe).
// C/D mapping: col=lane&15, row=(lane>>4)*4+reg  [m89-verified].
template <typename TIN>
__global__ __launch_bounds__(256) void transform_mfma_k(
    const TIN* __restrict__ in, const float* __restrict__ Wl,
    const float* __restrict__ Wr, ushort_t* __restrict__ outl,
    ushort_t* __restrict__ outr) {
  const int wid = blockIdx.x * 4 + (threadIdx.x >> 6);
  if (wid >= NSTRIP) return;
  const int lane = threadIdx.x & 63;
  const int row = lane & 15;
  const int kb = lane >> 4;  // k-block 0..3 (8 contiguous k each)

  // B fragments: tile t<4 -> Wl cols, t>=4 -> Wr cols
  bf16x8 Bfrag[8][2];
#pragma unroll
  for (int t = 0; t < 8; ++t) {
    const float* W = (t < 4) ? Wl : Wr;
    const int j = (t & 3) * 16 + row;  // output channel = W row
#pragma unroll
    for (int h = 0; h < 2; ++h) {
      const float* p = W + j * CH + h * 32 + kb * 8;
      float4 w0 = *(const float4*)p;
      float4 w1 = *(const float4*)(p + 4);
      bf16x8 b;
      b[0] = (short)f2bf(w0.x); b[1] = (short)f2bf(w0.y);
      b[2] = (short)f2bf(w0.z); b[3] = (short)f2bf(w0.w);
      b[4] = (short)f2bf(w1.x); b[5] = (short)f2bf(w1.y);
      b[6] = (short)f2bf(w1.z); b[7] = (short)f2bf(w1.w);
      Bfrag[t][h] = b;
    }
  }

  // A fragments for this 16-node strip
  const int n0 = wid * 16;
  bf16x8 Afrag[2];
#pragma unroll
  for (int h = 0; h < 2; ++h) {
    if constexpr (sizeof(TIN) == 4) {
      const float* p = (const float*)in + (size_t)(n0 + row) * CH + h * 32 + kb * 8;
      float4 a0 = *(const float4*)p;
      float4 a1 = *(const float4*)(p + 4);
      bf16x8 a;
      a[0] = (short)f2bf(a0.x); a[1] = (short)f2bf(a0.y);
      a[2] = (short)f2bf(a0.z); a[3] = (short)f2bf(a0.w);
      a[4] = (short)f2bf(a1.x); a[5] = (short)f2bf(a1.y);
      a[6] = (short)f2bf(a1.z); a[7] = (short)f2bf(a1.w);
      Afrag[h] = a;
    } else {
      const ushort_t* p = (const ushort_t*)in + (size_t)(n0 + row) * CH + h * 32 + kb * 8;
      Afrag[h] = *(const bf16x8*)p;  // 16B aligned direct bf16 load
    }
  }

  f32x4 acc[8];
#pragma unroll
  for (int t = 0; t < 8; ++t) {
    acc[t] = (f32x4){0.f, 0.f, 0.f, 0.f};
    acc[t] = __builtin_amdgcn_mfma_f32_16x16x32_bf16(Afrag[0], Bfrag[t][0],
                                                     acc[t], 0, 0, 0);
    acc[t] = __builtin_amdgcn_mfma_f32_16x16x32_bf16(Afrag[1], Bfrag[t][1],
                                                     acc[t], 0, 0, 0);
  }

  const int orow = (lane >> 4) * 4;
#pragma unroll
  for (int t = 0; t < 4; ++t)
#pragma unroll
    for (int i = 0; i < 4; ++i)
      outl[(size_t)(n0 + orow + i) * CH + t * 16 + row] = f2bf(acc[t][i]);
#pragma unroll
  for (int t = 4; t < 8; ++t)
#pragma unroll
    for (int i = 0; i < 4; ++i)
      outr[(size_t)(n0 + orow + i) * CH + (t - 4) * 16 + row] = f2bf(acc[t][i]);
}

// ---------------- pair-packed gather + mean + bias + relu (+ pool) ----------------
// lane = channel-PAIR (uint = 2 bf16); half = lane>>5: two halves process
// alternating edges; one shfl_xor(32) pair per node merges halves.
template <int MODE>
__global__ __launch_bounds__(256) void gather_k(
    const uint_t* __restrict__ glu, const uint_t* __restrict__ gru,
    const float* __restrict__ bl, const int* __restrict__ rowptr,
    const int* __restrict__ col, uint_t* __restrict__ outu,
    const int* __restrict__ batch, float* __restrict__ gsum,
    int* __restrict__ gcnt) {
  const int lane = threadIdx.x & 63;
  const int half = lane >> 5;
  const int cp = lane & 31;  // channel pair 0..31
  const float bE = bl[2 * cp], bO = bl[2 * cp + 1];
  const int wid = blockIdx.x * (blockDim.x >> 6) + (threadIdx.x >> 6);
  const int nw = gridDim.x * (blockDim.x >> 6);
  const int per = (N_NODES + nw - 1) / nw;
  int ns = wid * per;
  int ne = ns + per;
  if (ne > N_NODES) ne = N_NODES;
  if (ns >= ne) return;

  int curg = -1;
  float paccE = 0.f, paccO = 0.f;
  int pcnt = 0;

  for (int n = ns; n < ne; ++n) {
    const int eb = rowptr[n], ee = rowptr[n + 1];
    float e0 = 0.f, o0 = 0.f, e1 = 0.f, o1 = 0.f;
    float e2 = 0.f, o2 = 0.f, e3 = 0.f, o3 = 0.f;
    int j = eb + half;
    for (; j + 6 < ee; j += 8) {
      int c0 = col[j], c1 = col[j + 2], c4 = col[j + 4], c6 = col[j + 6];
      uint_t u0 = glu[(size_t)c0 * 32 + cp];
      uint_t u1 = glu[(size_t)c1 * 32 + cp];
      uint_t u2 = glu[(size_t)c4 * 32 + cp];
      uint_t u3 = glu[(size_t)c6 * 32 + cp];
      e0 += bfE(u0); o0 += bfO(u0);
      e1 += bfE(u1); o1 += bfO(u1);
      e2 += bfE(u2); o2 += bfO(u2);
      e3 += bfE(u3); o3 += bfO(u3);
    }
    for (; j < ee; j += 2) {
      uint_t u = glu[(size_t)col[j] * 32 + cp];
      e0 += bfE(u); o0 += bfO(u);
    }
    float sE = (e0 + e1) + (e2 + e3);
    float sO = (o0 + o1) + (o2 + o3);
    sE += __shfl_xor(sE, 32);
    sO += __shfl_xor(sO, 32);
    const int deg = ee - eb;
    const float inv = deg > 0 ? 1.f / (float)deg : 1.f;
    const uint_t ug = gru[(size_t)n * 32 + cp];
    const float rE = fmaxf(fmaf(sE, inv, bE + bfE(ug)), 0.f);
    const float rO = fmaxf(fmaf(sO, inv, bO + bfO(ug)), 0.f);
    if (MODE == 0) {
      if (half == 0)
        outu[(size_t)n * 32 + cp] = ((uint_t)f2bf(rO) << 16) | f2bf(rE);
    } else {
      int g = batch[n];
      if (g != curg) {
        if (curg >= 0 && half == 0) {
          atomicAdd(&gsum[curg * CH + 2 * cp], paccE);
          atomicAdd(&gsum[curg * CH + 2 * cp + 1], paccO);
          if (lane == 0) atomicAdd(&gcnt[curg], pcnt);
        }
        curg = g;
        paccE = 0.f;
        paccO = 0.f;
        pcnt = 0;
      }
      paccE += rE;
      paccO += rO;
      pcnt++;
    }
  }
  if (MODE == 1 && curg >= 0 && half == 0) {
    atomicAdd(&gsum[curg * CH + 2 * cp], paccE);
    atomicAdd(&gsum[curg * CH + 2 * cp + 1], paccO);
    if (lane == 0) atomicAdd(&gcnt[curg], pcnt);
  }
}

// ---------------- final projection ----------------
__global__ void final_k(const float* __restrict__ gsum, const int* __restrict__ gcnt,
                        const float* __restrict__ Wc, const float* __restrict__ bc,
                        float* __restrict__ out) {
  __shared__ float Wcs[OC * CH];
  __shared__ float bcs[OC];
  for (int i = threadIdx.x; i < OC * CH; i += blockDim.x) Wcs[i] = Wc[i];
  if (threadIdx.x < OC) bcs[threadIdx.x] = bc[threadIdx.x];
  __syncthreads();
  int g = threadIdx.x;
  float c = (float)gcnt[g];
  float inv = c > 0.f ? 1.f / c : 1.f;
  float gr[CH];
#pragma unroll
  for (int k = 0; k < CH; ++k) gr[k] = gsum[g * CH + k] * inv;
#pragma unroll
  for (int o = 0; o < OC; ++o) {
    float acc = bcs[o];
#pragma unroll
    for (int k = 0; k < CH; ++k) acc += gr[k] * Wcs[o * CH + k];
    out[g * OC + o] = acc;
  }
}

extern "C" void kernel_launch(void* const* d_in, const int* in_sizes, int n_in,
                              void* d_out, int out_size, void* d_ws, size_t ws_size,
                              hipStream_t stream) {
  const float* x   = (const float*)d_in[0];
  const int*   ei  = (const int*)d_in[1];
  const int*   bat = (const int*)d_in[2];
  const float* W1l = (const float*)d_in[3];
  const float* b1l = (const float*)d_in[4];
  const float* W1r = (const float*)d_in[5];
  const float* W2l = (const float*)d_in[6];
  const float* b2l = (const float*)d_in[7];
  const float* W2r = (const float*)d_in[8];
  const float* Wc  = (const float*)d_in[9];
  const float* bc  = (const float*)d_in[10];
  float* out = (float*)d_out;

  char* ws = (char*)d_ws;
  // all node-feature buffers bf16 (12.8 MB each), no aliasing between stages:
  //   buf1: xl -> h2l     buf3: h1     buf2: xr -> h2r
  ushort_t* buf1 = (ushort_t*)(ws + 0);         // 12,800,000 B
  ushort_t* buf3 = (ushort_t*)(ws + 12800000);  // 12,800,000 B
  ushort_t* buf2 = (ushort_t*)(ws + 25600000);  // 12,800,000 B
  int*   tmp     = (int*)(ws + 0);              //  4,800,000 B (aliased w/ buf1; CSR phase only)
  int*   rp      = (int*)(ws + 51200000);       //    400,128 B (incl pad)
  int*   col     = (int*)(ws + 51600128);       //  4,800,000 B
  int*   gbase   = (int*)(ws + 56400128);       //      1,024 B
  int*   boff    = (int*)(ws + 56401152);       //      1,024 B
  int*   cursor  = (int*)(ws + 56402176);       //      1,024 B
  float* gsum    = (float*)(ws + 56403200);     //     65,536 B
  int*   gcnt    = (int*)(ws + 56468736);       //      1,024 B

  const int* src = ei;
  const int* dst = ei + N_EDGES;

  hipMemsetAsync(gbase, 0, NBUK * sizeof(int), stream);
  hipMemsetAsync(gsum, 0, (size_t)NG * CH * sizeof(float) + NG * sizeof(int), stream);

  // ---- CSR build (bucketed counting sort) ----
  countA_k<<<NBLKA, 256, 0, stream>>>(dst, gbase);
  scanB_k<<<1, 256, 0, stream>>>(gbase, boff, cursor);
  scatterA_k<<<NBLKA, 256, 0, stream>>>(src, dst, cursor, tmp);
  csrC_k<<<NBUK, 512, 0, stream>>>(tmp, boff, rp, col);

  // ---- layer 1: x(f32) -> xl(buf1), xr(buf2); gather -> h1(buf3) ----
  transform_mfma_k<float><<<(NSTRIP + 3) / 4, 256, 0, stream>>>(x, W1l, W1r,
                                                                buf1, buf2);
  gather_k<0><<<2048, 256, 0, stream>>>((const uint_t*)buf1, (const uint_t*)buf2,
                                        b1l, rp, col, (uint_t*)buf3,
                                        nullptr, nullptr, nullptr);
  // ---- layer 2: h1(buf3) -> h2l(buf1), h2r(buf2); gather+pool ----
  transform_mfma_k<ushort_t><<<(NSTRIP + 3) / 4, 256, 0, stream>>>(buf3, W2l, W2r,
                                                                   buf1, buf2);
  gather_k<1><<<2048, 256, 0, stream>>>((const uint_t*)buf1, (const uint_t*)buf2,
                                        b2l, rp, col, nullptr,
                                        bat, gsum, gcnt);
  // ---- classify ----
  final_k<<<1, 256, 0, stream>>>(gsum, gcnt, Wc, bc, out);
}